// Round 1
// baseline (1976.344 us; speedup 1.0000x reference)
//
#include <hip/hip_runtime.h>

// ---------------------------------------------------------------------------
// StrongFormPhysicsLoss: 4-phase pipeline
//   phase 0: zero workspace (memset)
//   phase 1: element pass  -> atomic scatter F_int/M_int/F_ext + elem sums
//   phase 2: node pass     -> masked sums over nodes
//   phase 3: finalize      -> scalar loss
// Workspace layout (floats): [F_int 3N][M_int 3N][F_ext 3N][Scal block]
// ---------------------------------------------------------------------------

struct Scal {
    double rkin2, e1, e2, Lsum;          // element-level sums
    double Fe2, F2, Mr2, Mp2;            // node-level masked sums
    unsigned int qmax_bits, Lmax_bits;   // float-as-uint maxes (values >= 0)
    unsigned int cnt_d, cnt_r, cnt_p;    // mask counts
};

__device__ __forceinline__ double waveSumD(double v) {
#pragma unroll
    for (int o = 32; o > 0; o >>= 1) v += __shfl_down(v, o, 64);
    return v;
}
__device__ __forceinline__ float waveMaxF(float v) {
#pragma unroll
    for (int o = 32; o > 0; o >>= 1) v = fmaxf(v, __shfl_down(v, o, 64));
    return v;
}
__device__ __forceinline__ unsigned waveSumU(unsigned v) {
#pragma unroll
    for (int o = 32; o > 0; o >>= 1) v += __shfl_down(v, o, 64);
    return v;
}

// block = 256 threads = 4 waves
__device__ __forceinline__ void blockAtomicAddD(double v, double* dst, double* smem) {
    v = waveSumD(v);
    const int lane = threadIdx.x & 63, wid = threadIdx.x >> 6;
    if (lane == 0) smem[wid] = v;
    __syncthreads();
    if (threadIdx.x == 0) {
        double r = smem[0] + smem[1] + smem[2] + smem[3];
        atomicAdd(dst, r);
    }
    __syncthreads();
}
__device__ __forceinline__ void blockAtomicMaxF(float v, unsigned int* dst, float* smem) {
    v = waveMaxF(v);
    const int lane = threadIdx.x & 63, wid = threadIdx.x >> 6;
    if (lane == 0) smem[wid] = v;
    __syncthreads();
    if (threadIdx.x == 0) {
        float r = fmaxf(fmaxf(smem[0], smem[1]), fmaxf(smem[2], smem[3]));
        atomicMax(dst, __float_as_uint(fmaxf(r, 0.0f)));
    }
    __syncthreads();
}
__device__ __forceinline__ void blockAtomicAddU(unsigned v, unsigned int* dst, unsigned* smem) {
    v = waveSumU(v);
    const int lane = threadIdx.x & 63, wid = threadIdx.x >> 6;
    if (lane == 0) smem[wid] = v;
    __syncthreads();
    if (threadIdx.x == 0) {
        atomicAdd(dst, smem[0] + smem[1] + smem[2] + smem[3]);
    }
    __syncthreads();
}

__global__ __launch_bounds__(256) void elem_pass(
    const float* __restrict__ pred,      // [N,3]  (u_x, u_z, phi)
    const float* __restrict__ grad_ux,   // [N,3]
    const float* __restrict__ grad_uz,   // [N,3]
    const float* __restrict__ grad_phi,  // [N,3]
    const float* __restrict__ prop_E,    // [E]
    const float* __restrict__ prop_A,    // [E]
    const float* __restrict__ prop_I22,  // [E]
    const float* __restrict__ elemL,     // [E]
    const float* __restrict__ dirs,      // [E,3]
    const float* __restrict__ load,      // [E,3]
    const int*   __restrict__ conn,      // [E,2]
    float* __restrict__ F_int,           // [N,3]
    float* __restrict__ M_int,           // [N,3]
    float* __restrict__ F_ext,           // [N,3]
    Scal* sc, int n_elems)
{
    __shared__ double smD[4];
    __shared__ float  smF[4];

    double s_rkin2 = 0.0, s_e1 = 0.0, s_e2 = 0.0, s_Lsum = 0.0;
    float m_q = 0.0f, m_L = 0.0f;

    const int stride = gridDim.x * blockDim.x;
    for (int e = blockIdx.x * blockDim.x + threadIdx.x; e < n_elems; e += stride) {
        const int i = conn[2 * e];
        const int j = conn[2 * e + 1];

        const float x0 = dirs[3 * e], x1 = dirs[3 * e + 1], x2 = dirs[3 * e + 2];

        // local axes
        const bool par = fabsf(x1) > 0.99f;
        // ref = par ? (0,0,1) : (0,1,0)
        float z0, z1, z2;
        if (par) { // cross(x, (0,0,1)) = (x1, -x0, 0)
            z0 = x1; z1 = -x0; z2 = 0.0f;
        } else {   // cross(x, (0,1,0)) = (-x2, 0, x0)
            z0 = -x2; z1 = 0.0f; z2 = x0;
        }
        float zn = fmaxf(sqrtf(z0 * z0 + z1 * z1 + z2 * z2), 1e-8f);
        z0 /= zn; z1 /= zn; z2 /= zn;
        // y = cross(z, x)
        float y0 = z1 * x2 - z2 * x1;
        float y1 = z2 * x0 - z0 * x2;
        float y2 = z0 * x1 - z1 * x0;
        float yn = fmaxf(sqrtf(y0 * y0 + y1 * y1 + y2 * y2), 1e-8f);
        y0 /= yn; y1 /= yn; y2 /= yn;

        // node gathers
        const float uxi = pred[3 * i], uzi = pred[3 * i + 1], phii = pred[3 * i + 2];
        const float uxj = pred[3 * j], uzj = pred[3 * j + 1], phij = pred[3 * j + 2];
        const float dux = uxj - uxi, duz = uzj - uzi;

        const float Le   = elemL[e];
        const float invL = 1.0f / Le;
        const float EA   = prop_E[e] * prop_A[e];
        const float EI   = prop_E[e] * prop_I22[e];

        const float du_ax  = dux * x0 + duz * x2;
        const float eps_fd = du_ax * invL;
        const float N_fd   = EA * eps_fd;
        const float du_tr  = dux * z0 + duz * z2;
        const float kappa_fd = (phij - phii) * invL;

        const float EIL = EI * invL, EIL2 = EIL * invL, EIL3 = EIL2 * invL;
        const float V_fd = 12.0f * EIL3 * du_tr - 6.0f * EIL2 * (phii + phij);
        const float M_yi = 6.0f * EIL2 * du_tr - EIL * (4.0f * phii + 2.0f * phij);
        const float M_yj = 6.0f * EIL2 * du_tr - EIL * (2.0f * phii + 4.0f * phij);

        // autograd strain terms
        const float gxi = grad_ux[3 * i] * x0 + grad_ux[3 * i + 1] * x1 + grad_ux[3 * i + 2] * x2;
        const float gzi = grad_uz[3 * i] * x0 + grad_uz[3 * i + 1] * x1 + grad_uz[3 * i + 2] * x2;
        const float gxj = grad_ux[3 * j] * x0 + grad_ux[3 * j + 1] * x1 + grad_ux[3 * j + 2] * x2;
        const float gzj = grad_uz[3 * j] * x0 + grad_uz[3 * j + 1] * x1 + grad_uz[3 * j + 2] * x2;
        const float eps_ag = 0.5f * ((x0 * gxi + x2 * gzi) + (x0 * gxj + x2 * gzj));
        const float kap_i = grad_phi[3 * i] * x0 + grad_phi[3 * i + 1] * x1 + grad_phi[3 * i + 2] * x2;
        const float kap_j = grad_phi[3 * j] * x0 + grad_phi[3 * j + 1] * x1 + grad_phi[3 * j + 2] * x2;
        const float kappa_ag = 0.5f * (kap_i + kap_j);

        // edge force
        const float Fe0 = N_fd * x0 + V_fd * z0;
        const float Fe1 = N_fd * x1 + V_fd * z1;
        const float Fe2 = N_fd * x2 + V_fd * z2;
        atomicAdd(&F_int[3 * i],     Fe0);
        atomicAdd(&F_int[3 * i + 1], Fe1);
        atomicAdd(&F_int[3 * i + 2], Fe2);
        atomicAdd(&F_int[3 * j],     -Fe0);
        atomicAdd(&F_int[3 * j + 1], -Fe1);
        atomicAdd(&F_int[3 * j + 2], -Fe2);

        atomicAdd(&M_int[3 * i],     M_yi * y0);
        atomicAdd(&M_int[3 * i + 1], M_yi * y1);
        atomicAdd(&M_int[3 * i + 2], M_yi * y2);
        atomicAdd(&M_int[3 * j],     M_yj * y0);
        atomicAdd(&M_int[3 * j + 1], M_yj * y1);
        atomicAdd(&M_int[3 * j + 2], M_yj * y2);

        const float l0 = load[3 * e], l1 = load[3 * e + 1], l2 = load[3 * e + 2];
        const float hl = 0.5f * Le;
        atomicAdd(&F_ext[3 * i],     l0 * hl);
        atomicAdd(&F_ext[3 * i + 1], l1 * hl);
        atomicAdd(&F_ext[3 * i + 2], l2 * hl);
        atomicAdd(&F_ext[3 * j],     l0 * hl);
        atomicAdd(&F_ext[3 * j + 1], l1 * hl);
        atomicAdd(&F_ext[3 * j + 2], l2 * hl);

        // element-level reductions
        const float dw_ds = du_tr * invL;
        const float r_kin = 0.5f * (phii + phij) - dw_ds;
        s_rkin2 += (double)(r_kin * r_kin);
        const float d1 = eps_ag - eps_fd;
        s_e1 += (double)(d1 * d1);
        const float d2 = kappa_ag - kappa_fd;
        s_e2 += (double)(d2 * d2);
        s_Lsum += (double)Le;
        m_q = fmaxf(m_q, fmaxf(fabsf(l0), fmaxf(fabsf(l1), fabsf(l2))));
        m_L = fmaxf(m_L, Le);
    }

    blockAtomicAddD(s_rkin2, &sc->rkin2, smD);
    blockAtomicAddD(s_e1,    &sc->e1,    smD);
    blockAtomicAddD(s_e2,    &sc->e2,    smD);
    blockAtomicAddD(s_Lsum,  &sc->Lsum,  smD);
    blockAtomicMaxF(m_q, &sc->qmax_bits, smF);
    blockAtomicMaxF(m_L, &sc->Lmax_bits, smF);
}

__global__ __launch_bounds__(256) void node_pass(
    const float* __restrict__ F_int,
    const float* __restrict__ M_int,
    const float* __restrict__ F_ext,
    const float* __restrict__ bc_disp,
    const float* __restrict__ bc_rot,
    Scal* sc, int n_nodes)
{
    __shared__ double smD[4];
    __shared__ unsigned smU[4];

    double sFe2 = 0.0, sF2 = 0.0, sMr2 = 0.0, sMp2 = 0.0;
    unsigned cd = 0, cr = 0, cp = 0;

    const int stride = gridDim.x * blockDim.x;
    for (int k = blockIdx.x * blockDim.x + threadIdx.x; k < n_nodes; k += stride) {
        const float bd = bc_disp[k], br = bc_rot[k];
        const bool free_d = bd < 0.5f;
        const bool free_r = br < 0.5f;
        const bool pin    = (bd > 0.5f) && free_r;

        const float fe0 = F_ext[3 * k], fe1 = F_ext[3 * k + 1], fe2 = F_ext[3 * k + 2];
        if (free_d) {
            const float f0 = F_int[3 * k] + fe0;
            const float f1 = F_int[3 * k + 1] + fe1;
            const float f2 = F_int[3 * k + 2] + fe2;
            sFe2 += (double)(fe0 * fe0 + fe1 * fe1 + fe2 * fe2);
            sF2  += (double)(f0 * f0 + f1 * f1 + f2 * f2);
            cd++;
        }
        if (free_r | pin) {
            const float m0 = M_int[3 * k], m1 = M_int[3 * k + 1], m2 = M_int[3 * k + 2];
            const double mm = (double)(m0 * m0 + m1 * m1 + m2 * m2);
            if (free_r) { sMr2 += mm; cr++; }
            if (pin)    { sMp2 += mm; cp++; }
        }
    }

    blockAtomicAddD(sFe2, &sc->Fe2, smD);
    blockAtomicAddD(sF2,  &sc->F2,  smD);
    blockAtomicAddD(sMr2, &sc->Mr2, smD);
    blockAtomicAddD(sMp2, &sc->Mp2, smD);
    blockAtomicAddU(cd, &sc->cnt_d, smU);
    blockAtomicAddU(cr, &sc->cnt_r, smU);
    blockAtomicAddU(cp, &sc->cnt_p, smU);
}

__global__ void finalize(const Scal* sc, float* out, int n_elems)
{
    const double cnt_d = (double)max(sc->cnt_d, 1u);
    const double cnt_r = (double)max(sc->cnt_r, 1u);
    const double cnt_p = (double)max(sc->cnt_p, 1u);

    const double F_char = fmax(sqrt(sc->Fe2 / (cnt_d * 3.0)), 1.0);
    const double L_force = sc->F2 / (cnt_d * 3.0) / (F_char * F_char);

    const double qmax = fmax((double)__uint_as_float(sc->qmax_bits), 1.0);
    const double Lmax = (double)__uint_as_float(sc->Lmax_bits);
    const double M_char = fmax(qmax * Lmax * sc->Lsum / 8.0, 1.0);

    const double L_moment  = sc->Mr2 / (cnt_r * 3.0) / (M_char * M_char);
    const double L_neumann = sc->Mp2 / (cnt_p * 3.0) / (M_char * M_char);

    const double inv_ne = 1.0 / (double)n_elems;
    const double L_kin = sc->rkin2 * inv_ne;
    const double L_consist = sc->e1 * inv_ne + sc->e2 * inv_ne;

    // W_FORCE=1, W_MOMENT=1, W_KIN=0.1, W_NEUMANN=1, W_CONSISTENCY=1
    out[0] = (float)(L_force + L_moment + L_neumann + 0.1 * L_kin + L_consist);
}

extern "C" void kernel_launch(void* const* d_in, const int* in_sizes, int n_in,
                              void* d_out, int out_size, void* d_ws, size_t ws_size,
                              hipStream_t stream)
{
    const float* pred     = (const float*)d_in[0];
    const float* grad_ux  = (const float*)d_in[1];
    const float* grad_uz  = (const float*)d_in[2];
    const float* grad_phi = (const float*)d_in[3];
    const float* prop_E   = (const float*)d_in[4];
    const float* prop_A   = (const float*)d_in[5];
    const float* prop_I22 = (const float*)d_in[6];
    const float* elemL    = (const float*)d_in[7];
    const float* dirs     = (const float*)d_in[8];
    const float* load     = (const float*)d_in[9];
    const float* bc_disp  = (const float*)d_in[10];
    const float* bc_rot   = (const float*)d_in[11];
    const int*   conn     = (const int*)d_in[12];

    const int n_elems = in_sizes[4];   // prop_E
    const int n_nodes = in_sizes[10];  // bc_disp (N,1)

    float* F_int = (float*)d_ws;
    float* M_int = F_int + (size_t)3 * n_nodes;
    float* F_ext = M_int + (size_t)3 * n_nodes;
    const size_t node_bytes = (size_t)9 * n_nodes * sizeof(float);
    // node_bytes = 36,000,000 — divisible by 8, Scal is 8-byte aligned
    Scal* sc = (Scal*)((char*)d_ws + node_bytes);

    hipMemsetAsync(d_ws, 0, node_bytes + sizeof(Scal), stream);

    elem_pass<<<4096, 256, 0, stream>>>(pred, grad_ux, grad_uz, grad_phi,
                                        prop_E, prop_A, prop_I22, elemL,
                                        dirs, load, conn,
                                        F_int, M_int, F_ext, sc, n_elems);
    node_pass<<<2048, 256, 0, stream>>>(F_int, M_int, F_ext, bc_disp, bc_rot, sc, n_nodes);
    finalize<<<1, 1, 0, stream>>>(sc, (float*)d_out, n_elems);
}